// Round 1
// baseline (577.678 us; speedup 1.0000x reference)
//
#include <hip/hip_runtime.h>
#include <hip/hip_bf16.h>

// ---------------------------------------------------------------------------
// GCN 2-layer + mean-pool + linear head, all f32.
// Pipeline per call (deterministic, rebuilt from scratch each call):
//   1. histogram in-degree (int atomics)            -> cnt
//   2. dinv[i] = rsqrt(cnt[i]+1)
//   3. exclusive scan -> row_ptr (CSR)
//   4. fill CSR col (src ids)
//   5. hs1 = (x @ W1) * dinv[row]          (GEMM, dinv fused in epilogue)
//   6. r1  = relu(dinv*(sum_nbr hs1 + hs1_self) + b1)   (pull-gather agg)
//   7. hs2 = (r1 @ W2) * dinv[row]
//   8. r2  = relu(dinv*(sum_nbr hs2 + hs2_self) + b2)
//   9. pooled sums per graph (run-length batched atomics, batch is sorted)
//  10. out[g] = (s[g] . Wlin)/cnt[g] + blin
// ---------------------------------------------------------------------------

__global__ void hist_kernel(const int* __restrict__ dst, int E, int* __restrict__ cnt) {
    int i = blockIdx.x * blockDim.x + threadIdx.x;
    int stride = gridDim.x * blockDim.x;
    for (; i < E; i += stride) atomicAdd(&cnt[dst[i]], 1);
}

__global__ void dinv_kernel(const int* __restrict__ cnt, float* __restrict__ dinv, int N) {
    int i = blockIdx.x * blockDim.x + threadIdx.x;
    if (i < N) dinv[i] = rsqrtf((float)cnt[i] + 1.0f);
}

__global__ __launch_bounds__(1024) void scan1_kernel(const int* __restrict__ cnt,
                                                     int* __restrict__ rp,
                                                     int* __restrict__ bsum, int N) {
    __shared__ int s[1024];
    int t = threadIdx.x;
    int i = blockIdx.x * 1024 + t;
    int v = (i < N) ? cnt[i] : 0;
    s[t] = v;
    __syncthreads();
    for (int off = 1; off < 1024; off <<= 1) {
        int x = (t >= off) ? s[t - off] : 0;
        __syncthreads();
        s[t] += x;
        __syncthreads();
    }
    if (i < N) rp[i + 1] = s[t];
    if (t == 1023) bsum[blockIdx.x] = s[1023];
}

__global__ __launch_bounds__(1024) void scan2_kernel(int* __restrict__ bsum, int nb) {
    __shared__ int s[1024];
    int t = threadIdx.x;
    int v = (t < nb) ? bsum[t] : 0;
    s[t] = v;
    __syncthreads();
    for (int off = 1; off < 1024; off <<= 1) {
        int x = (t >= off) ? s[t - off] : 0;
        __syncthreads();
        s[t] += x;
        __syncthreads();
    }
    if (t < nb) bsum[t] = s[t] - v;  // exclusive block offset
}

__global__ __launch_bounds__(1024) void scan3_kernel(int* __restrict__ rp,
                                                     const int* __restrict__ bsum, int N) {
    int i = blockIdx.x * 1024 + threadIdx.x;
    if (i < N) rp[i + 1] += bsum[blockIdx.x];
    if (i == 0) rp[0] = 0;
}

__global__ void fill_kernel(const int* __restrict__ src, const int* __restrict__ dst, int E,
                            const int* __restrict__ rp, int* __restrict__ cur,
                            int* __restrict__ col) {
    int i = blockIdx.x * blockDim.x + threadIdx.x;
    int stride = gridDim.x * blockDim.x;
    for (; i < E; i += stride) {
        int d = dst[i];
        int pos = rp[d] + atomicAdd(&cur[d], 1);
        col[pos] = src[i];
    }
}

// C[row][c] = (sum_k A[row][k]*W[k][c]) * dinv[row]   (M x 128) @ (128 x 128)
__global__ __launch_bounds__(256) void gemm128_kernel(const float* __restrict__ A,
                                                      const float* __restrict__ W,
                                                      const float* __restrict__ dinv,
                                                      float* __restrict__ C, int M) {
    __shared__ float Xt[64][68];   // 64 rows x 64 k (padded)
    __shared__ float Wt[64][128];  // 64 k x 128 cols
    int t = threadIdx.x;
    int r0 = blockIdx.x * 64;
    int cg = t & 31;   // cols cg*4 .. cg*4+3
    int rg = t >> 5;   // rows rg*8 .. rg*8+7
    float acc[8][4];
#pragma unroll
    for (int i = 0; i < 8; ++i)
#pragma unroll
        for (int j = 0; j < 4; ++j) acc[i][j] = 0.f;

    for (int kt = 0; kt < 128; kt += 64) {
        // stage X tile (64x64)
#pragma unroll
        for (int i = 0; i < 4; ++i) {
            int lin = (t + i * 256) * 4;  // 0..4095
            int r = lin >> 6;
            int kk = lin & 63;
            float4 v = make_float4(0.f, 0.f, 0.f, 0.f);
            int row = r0 + r;
            if (row < M) v = *(const float4*)&A[(size_t)row * 128 + kt + kk];
            *(float4*)&Xt[r][kk] = v;
        }
        // stage W tile (64x128)
#pragma unroll
        for (int i = 0; i < 8; ++i) {
            int lin = (t + i * 256) * 4;  // 0..8191
            int r = lin >> 7;
            int c = lin & 127;
            *(float4*)&Wt[r][c] = *(const float4*)&W[(kt + r) * 128 + c];
        }
        __syncthreads();
#pragma unroll 8
        for (int k = 0; k < 64; ++k) {
            float4 w = *(const float4*)&Wt[k][cg * 4];
#pragma unroll
            for (int i = 0; i < 8; ++i) {
                float xs = Xt[rg * 8 + i][k];
                acc[i][0] = fmaf(xs, w.x, acc[i][0]);
                acc[i][1] = fmaf(xs, w.y, acc[i][1]);
                acc[i][2] = fmaf(xs, w.z, acc[i][2]);
                acc[i][3] = fmaf(xs, w.w, acc[i][3]);
            }
        }
        __syncthreads();
    }
#pragma unroll
    for (int i = 0; i < 8; ++i) {
        int row = r0 + rg * 8 + i;
        if (row < M) {
            float d = dinv[row];
            float4 o = make_float4(acc[i][0] * d, acc[i][1] * d, acc[i][2] * d, acc[i][3] * d);
            *(float4*)&C[(size_t)row * 128 + cg * 4] = o;
        }
    }
}

// pull aggregation: one 32-lane group per node
__global__ __launch_bounds__(256) void agg_kernel(const float* __restrict__ hs,
                                                  const float* __restrict__ dinv,
                                                  const int* __restrict__ rp,
                                                  const int* __restrict__ col,
                                                  const float* __restrict__ bias,
                                                  float* __restrict__ out, int N) {
    int g = (int)((blockIdx.x * 256 + threadIdx.x) >> 5);
    int lane = threadIdx.x & 31;
    if (g >= N) return;
    const float4* hs4 = (const float4*)hs;
    float4 acc = hs4[(size_t)g * 32 + lane];  // self contribution (hs_i)
    int e = rp[g], end = rp[g + 1];
    for (; e + 1 < end; e += 2) {
        int j0 = col[e];
        int j1 = col[e + 1];
        float4 v0 = hs4[(size_t)j0 * 32 + lane];
        float4 v1 = hs4[(size_t)j1 * 32 + lane];
        acc.x += v0.x + v1.x;
        acc.y += v0.y + v1.y;
        acc.z += v0.z + v1.z;
        acc.w += v0.w + v1.w;
    }
    if (e < end) {
        int j = col[e];
        float4 v = hs4[(size_t)j * 32 + lane];
        acc.x += v.x;
        acc.y += v.y;
        acc.z += v.z;
        acc.w += v.w;
    }
    float d = dinv[g];
    float4 b = ((const float4*)bias)[lane];
    float4 o;
    o.x = fmaxf(fmaf(acc.x, d, b.x), 0.f);
    o.y = fmaxf(fmaf(acc.y, d, b.y), 0.f);
    o.z = fmaxf(fmaf(acc.z, d, b.z), 0.f);
    o.w = fmaxf(fmaf(acc.w, d, b.w), 0.f);
    ((float4*)out)[(size_t)g * 32 + lane] = o;
}

// pooling: each 32-lane group handles 32 consecutive nodes, run-length batched
__global__ __launch_bounds__(256) void pool_kernel(const float* __restrict__ r2,
                                                   const int* __restrict__ batch,
                                                   float* __restrict__ ps,
                                                   int* __restrict__ pc, int N) {
    int grp = (int)((blockIdx.x * 256 + threadIdx.x) >> 5);
    int lane = threadIdx.x & 31;
    int n0 = grp * 32;
    if (n0 >= N) return;
    int n1 = min(n0 + 32, N);
    const float4* r4 = (const float4*)r2;
    float4 acc = make_float4(0.f, 0.f, 0.f, 0.f);
    int curg = batch[n0];
    int cnt = 0;
    for (int n = n0; n < n1; ++n) {
        int gph = batch[n];
        if (gph != curg) {
            atomicAdd(&ps[curg * 128 + lane * 4 + 0], acc.x);
            atomicAdd(&ps[curg * 128 + lane * 4 + 1], acc.y);
            atomicAdd(&ps[curg * 128 + lane * 4 + 2], acc.z);
            atomicAdd(&ps[curg * 128 + lane * 4 + 3], acc.w);
            if (lane == 0) atomicAdd(&pc[curg], cnt);
            acc = make_float4(0.f, 0.f, 0.f, 0.f);
            cnt = 0;
            curg = gph;
        }
        float4 v = r4[(size_t)n * 32 + lane];
        acc.x += v.x;
        acc.y += v.y;
        acc.z += v.z;
        acc.w += v.w;
        cnt++;
    }
    atomicAdd(&ps[curg * 128 + lane * 4 + 0], acc.x);
    atomicAdd(&ps[curg * 128 + lane * 4 + 1], acc.y);
    atomicAdd(&ps[curg * 128 + lane * 4 + 2], acc.z);
    atomicAdd(&ps[curg * 128 + lane * 4 + 3], acc.w);
    if (lane == 0) atomicAdd(&pc[curg], cnt);
}

// out[g] = (ps[g] . Wlin) / max(pc[g],1) + blin   — one wave per graph
__global__ __launch_bounds__(256) void final_kernel(const float* __restrict__ ps,
                                                    const int* __restrict__ pc,
                                                    const float* __restrict__ Wlin,
                                                    const float* __restrict__ blin,
                                                    float* __restrict__ out, int G) {
    int g = (int)((blockIdx.x * 256 + threadIdx.x) >> 6);
    int lane = threadIdx.x & 63;
    if (g >= G) return;
    float2 s = ((const float2*)ps)[g * 64 + lane];
    float2 w = ((const float2*)Wlin)[lane];
    float v = s.x * w.x + s.y * w.y;
#pragma unroll
    for (int off = 32; off > 0; off >>= 1) v += __shfl_down(v, off);
    if (lane == 0) {
        float c = (float)max(pc[g], 1);
        out[g] = v / c + blin[0];
    }
}

extern "C" void kernel_launch(void* const* d_in, const int* in_sizes, int n_in,
                              void* d_out, int out_size, void* d_ws, size_t ws_size,
                              hipStream_t stream) {
    const float* x    = (const float*)d_in[0];
    const float* W1   = (const float*)d_in[1];
    const float* b1   = (const float*)d_in[2];
    const float* W2   = (const float*)d_in[3];
    const float* b2   = (const float*)d_in[4];
    const float* Wlin = (const float*)d_in[5];
    const float* blin = (const float*)d_in[6];
    const int*   ei   = (const int*)d_in[7];   // [2, E]
    const int*   batch= (const int*)d_in[8];   // [N]
    (void)d_in[9];

    const int N = in_sizes[0] / 128;
    const int E = in_sizes[7] / 2;
    const int G = out_size;  // [G,1] output

    const int* srcp = ei;
    const int* dstp = ei + E;

    // workspace carve-up
    char* w = (char*)d_ws;
    size_t off = 0;
    auto carve = [&](size_t bytes) {
        size_t o = off;
        off = (off + bytes + 255) & ~(size_t)255;
        return (void*)(w + o);
    };
    float* bufA = (float*)carve((size_t)N * 128 * 4);  // hs (GEMM out)
    float* bufB = (float*)carve((size_t)N * 128 * 4);  // relu(agg) out
    float* dinv = (float*)carve((size_t)N * 4);
    int*   cnt  = (int*)carve((size_t)N * 4);
    int*   rp   = (int*)carve((size_t)(N + 1) * 4);
    int*   bsum = (int*)carve(1024 * 4);
    int*   col  = (int*)carve((size_t)E * 4);
    float* ps   = (float*)carve((size_t)G * 128 * 4);
    int*   pc   = (int*)carve((size_t)G * 4);
    (void)ws_size;

    const int nb = (N + 1023) / 1024;

    // 1. degree histogram
    hipMemsetAsync(cnt, 0, (size_t)N * 4, stream);
    hist_kernel<<<2048, 256, 0, stream>>>(dstp, E, cnt);
    // 2. dinv
    dinv_kernel<<<(N + 255) / 256, 256, 0, stream>>>(cnt, dinv, N);
    // 3. scan -> row_ptr
    scan1_kernel<<<nb, 1024, 0, stream>>>(cnt, rp, bsum, N);
    scan2_kernel<<<1, 1024, 0, stream>>>(bsum, nb);
    scan3_kernel<<<nb, 1024, 0, stream>>>(rp, bsum, N);
    // 4. CSR fill
    hipMemsetAsync(cnt, 0, (size_t)N * 4, stream);
    fill_kernel<<<2048, 256, 0, stream>>>(srcp, dstp, E, rp, cnt, col);

    const int gemm_grid = (N + 63) / 64;
    const int agg_grid  = (int)(((size_t)N * 32 + 255) / 256);

    // layer 1
    gemm128_kernel<<<gemm_grid, 256, 0, stream>>>(x, W1, dinv, bufA, N);
    agg_kernel<<<agg_grid, 256, 0, stream>>>(bufA, dinv, rp, col, b1, bufB, N);
    // layer 2
    gemm128_kernel<<<gemm_grid, 256, 0, stream>>>(bufB, W2, dinv, bufA, N);
    agg_kernel<<<agg_grid, 256, 0, stream>>>(bufA, dinv, rp, col, b2, bufB, N);

    // pooling
    hipMemsetAsync(ps, 0, (size_t)G * 128 * 4, stream);
    hipMemsetAsync(pc, 0, (size_t)G * 4, stream);
    const int ngrp = (N + 31) / 32;
    pool_kernel<<<(int)(((size_t)ngrp * 32 + 255) / 256), 256, 0, stream>>>(bufB, batch, ps, pc, N);

    // head
    final_kernel<<<(G * 64 + 255) / 256, 256, 0, stream>>>(ps, pc, Wlin, blin, (float*)d_out, G);
}

// Round 2
// 466.176 us; speedup vs baseline: 1.2392x; 1.2392x over previous
//
#include <hip/hip_runtime.h>
#include <hip/hip_bf16.h>

// ---------------------------------------------------------------------------
// GCN 2-layer + mean-pool + linear head.
// f32 math everywhere; intermediate feature maps stored as bf16 to halve
// gather/GEMM-A/pool memory traffic. CSR built per call (deterministic).
//   1. histogram in-degree (int atomics)            -> cnt
//   2. dinv[i] = rsqrt(cnt[i]+1)
//   3. exclusive scan -> row_ptr (CSR)
//   4. fill CSR col (src ids), nontemporal col store
//   5. hs1 = bf16((x @ W1) * dinv[row])             (GEMM f32 math)
//   6. r1  = bf16(relu(dinv*(sum_nbr hs1 + hs1_self) + b1))  (pull agg)
//   7. hs2 = bf16((r1 @ W2) * dinv[row])
//   8. r2  = bf16(relu(dinv*(sum_nbr hs2 + hs2_self) + b2))
//   9. pooled f32 sums per graph (run-length batched atomics, batch sorted)
//  10. out[g] = (s[g] . Wlin)/cnt[g] + blin
// ---------------------------------------------------------------------------

typedef unsigned int uint32;
typedef unsigned short ushort16;

__device__ __forceinline__ float bf2f(unsigned short u) {
    return __uint_as_float(((unsigned int)u) << 16);
}
__device__ __forceinline__ unsigned short f2bf(float f) {
    unsigned int u = __float_as_uint(f);
    return (unsigned short)((u + 0x7FFFu + ((u >> 16) & 1u)) >> 16);
}
__device__ __forceinline__ float4 bfu4_to_f4(ushort4 v) {
    return make_float4(bf2f(v.x), bf2f(v.y), bf2f(v.z), bf2f(v.w));
}

__global__ void hist_kernel(const int* __restrict__ dst, int E, int* __restrict__ cnt) {
    int i = blockIdx.x * blockDim.x + threadIdx.x;
    int stride = gridDim.x * blockDim.x;
    for (; i < E; i += stride) atomicAdd(&cnt[dst[i]], 1);
}

__global__ void dinv_kernel(const int* __restrict__ cnt, float* __restrict__ dinv, int N) {
    int i = blockIdx.x * blockDim.x + threadIdx.x;
    if (i < N) dinv[i] = rsqrtf((float)cnt[i] + 1.0f);
}

__global__ __launch_bounds__(1024) void scan1_kernel(const int* __restrict__ cnt,
                                                     int* __restrict__ rp,
                                                     int* __restrict__ bsum, int N) {
    __shared__ int s[1024];
    int t = threadIdx.x;
    int i = blockIdx.x * 1024 + t;
    int v = (i < N) ? cnt[i] : 0;
    s[t] = v;
    __syncthreads();
    for (int off = 1; off < 1024; off <<= 1) {
        int x = (t >= off) ? s[t - off] : 0;
        __syncthreads();
        s[t] += x;
        __syncthreads();
    }
    if (i < N) rp[i + 1] = s[t];
    if (t == 1023) bsum[blockIdx.x] = s[1023];
}

__global__ __launch_bounds__(1024) void scan2_kernel(int* __restrict__ bsum, int nb) {
    __shared__ int s[1024];
    int t = threadIdx.x;
    int v = (t < nb) ? bsum[t] : 0;
    s[t] = v;
    __syncthreads();
    for (int off = 1; off < 1024; off <<= 1) {
        int x = (t >= off) ? s[t - off] : 0;
        __syncthreads();
        s[t] += x;
        __syncthreads();
    }
    if (t < nb) bsum[t] = s[t] - v;  // exclusive block offset
}

__global__ __launch_bounds__(1024) void scan3_kernel(int* __restrict__ rp,
                                                     const int* __restrict__ bsum, int N) {
    int i = blockIdx.x * 1024 + threadIdx.x;
    if (i < N) rp[i + 1] += bsum[blockIdx.x];
    if (i == 0) rp[0] = 0;
}

__global__ void fill_kernel(const int* __restrict__ src, const int* __restrict__ dst, int E,
                            const int* __restrict__ rp, int* __restrict__ cur,
                            int* __restrict__ col) {
    int i = blockIdx.x * blockDim.x + threadIdx.x;
    int stride = gridDim.x * blockDim.x;
    for (; i < E; i += stride) {
        int d = dst[i];
        int s = src[i];
        int pos = rp[d] + atomicAdd(&cur[d], 1);
        __builtin_nontemporal_store(s, &col[pos]);
    }
}

// hs[row][c] = bf16((sum_k A[row][k]*W[k][c]) * dinv[row])  — A f32
__global__ __launch_bounds__(256) void gemm128_f32A(const float* __restrict__ A,
                                                    const float* __restrict__ W,
                                                    const float* __restrict__ dinv,
                                                    unsigned short* __restrict__ C, int M) {
    __shared__ float Xt[64][68];
    __shared__ float Wt[64][128];
    int t = threadIdx.x;
    int r0 = blockIdx.x * 64;
    int cg = t & 31;
    int rg = t >> 5;
    float acc[8][4];
#pragma unroll
    for (int i = 0; i < 8; ++i)
#pragma unroll
        for (int j = 0; j < 4; ++j) acc[i][j] = 0.f;

    for (int kt = 0; kt < 128; kt += 64) {
#pragma unroll
        for (int i = 0; i < 4; ++i) {
            int lin = (t + i * 256) * 4;
            int r = lin >> 6;
            int kk = lin & 63;
            float4 v = make_float4(0.f, 0.f, 0.f, 0.f);
            int row = r0 + r;
            if (row < M) v = *(const float4*)&A[(size_t)row * 128 + kt + kk];
            *(float4*)&Xt[r][kk] = v;
        }
#pragma unroll
        for (int i = 0; i < 8; ++i) {
            int lin = (t + i * 256) * 4;
            int r = lin >> 7;
            int c = lin & 127;
            *(float4*)&Wt[r][c] = *(const float4*)&W[(kt + r) * 128 + c];
        }
        __syncthreads();
#pragma unroll 8
        for (int k = 0; k < 64; ++k) {
            float4 w = *(const float4*)&Wt[k][cg * 4];
#pragma unroll
            for (int i = 0; i < 8; ++i) {
                float xs = Xt[rg * 8 + i][k];
                acc[i][0] = fmaf(xs, w.x, acc[i][0]);
                acc[i][1] = fmaf(xs, w.y, acc[i][1]);
                acc[i][2] = fmaf(xs, w.z, acc[i][2]);
                acc[i][3] = fmaf(xs, w.w, acc[i][3]);
            }
        }
        __syncthreads();
    }
#pragma unroll
    for (int i = 0; i < 8; ++i) {
        int row = r0 + rg * 8 + i;
        if (row < M) {
            float d = dinv[row];
            ushort4 o;
            o.x = f2bf(acc[i][0] * d);
            o.y = f2bf(acc[i][1] * d);
            o.z = f2bf(acc[i][2] * d);
            o.w = f2bf(acc[i][3] * d);
            *(ushort4*)&C[(size_t)row * 128 + cg * 4] = o;
        }
    }
}

// hs[row][c] = bf16((sum_k A[row][k]*W[k][c]) * dinv[row])  — A bf16
__global__ __launch_bounds__(256) void gemm128_bf16A(const unsigned short* __restrict__ A,
                                                     const float* __restrict__ W,
                                                     const float* __restrict__ dinv,
                                                     unsigned short* __restrict__ C, int M) {
    __shared__ float Xt[64][68];
    __shared__ float Wt[64][128];
    int t = threadIdx.x;
    int r0 = blockIdx.x * 64;
    int cg = t & 31;
    int rg = t >> 5;
    float acc[8][4];
#pragma unroll
    for (int i = 0; i < 8; ++i)
#pragma unroll
        for (int j = 0; j < 4; ++j) acc[i][j] = 0.f;

    for (int kt = 0; kt < 128; kt += 64) {
#pragma unroll
        for (int i = 0; i < 4; ++i) {
            int lin = (t + i * 256) * 4;
            int r = lin >> 6;
            int kk = lin & 63;
            float4 v = make_float4(0.f, 0.f, 0.f, 0.f);
            int row = r0 + r;
            if (row < M) {
                ushort4 u = *(const ushort4*)&A[(size_t)row * 128 + kt + kk];
                v = bfu4_to_f4(u);
            }
            *(float4*)&Xt[r][kk] = v;
        }
#pragma unroll
        for (int i = 0; i < 8; ++i) {
            int lin = (t + i * 256) * 4;
            int r = lin >> 7;
            int c = lin & 127;
            *(float4*)&Wt[r][c] = *(const float4*)&W[(kt + r) * 128 + c];
        }
        __syncthreads();
#pragma unroll 8
        for (int k = 0; k < 64; ++k) {
            float4 w = *(const float4*)&Wt[k][cg * 4];
#pragma unroll
            for (int i = 0; i < 8; ++i) {
                float xs = Xt[rg * 8 + i][k];
                acc[i][0] = fmaf(xs, w.x, acc[i][0]);
                acc[i][1] = fmaf(xs, w.y, acc[i][1]);
                acc[i][2] = fmaf(xs, w.z, acc[i][2]);
                acc[i][3] = fmaf(xs, w.w, acc[i][3]);
            }
        }
        __syncthreads();
    }
#pragma unroll
    for (int i = 0; i < 8; ++i) {
        int row = r0 + rg * 8 + i;
        if (row < M) {
            float d = dinv[row];
            ushort4 o;
            o.x = f2bf(acc[i][0] * d);
            o.y = f2bf(acc[i][1] * d);
            o.z = f2bf(acc[i][2] * d);
            o.w = f2bf(acc[i][3] * d);
            *(ushort4*)&C[(size_t)row * 128 + cg * 4] = o;
        }
    }
}

// pull aggregation, bf16 in/out: one 32-lane group per node (8B/lane/edge)
__global__ __launch_bounds__(256) void agg_bf16(const unsigned short* __restrict__ hs,
                                                const float* __restrict__ dinv,
                                                const int* __restrict__ rp,
                                                const int* __restrict__ col,
                                                const float* __restrict__ bias,
                                                unsigned short* __restrict__ out, int N) {
    int g = (int)((blockIdx.x * 256 + threadIdx.x) >> 5);
    int lane = threadIdx.x & 31;
    if (g >= N) return;
    const ushort4* h4 = (const ushort4*)hs;
    float4 acc = bfu4_to_f4(h4[(size_t)g * 32 + lane]);  // self (hs_i)
    int e = rp[g], end = rp[g + 1];
    for (; e + 3 < end; e += 4) {
        int j0 = col[e], j1 = col[e + 1], j2 = col[e + 2], j3 = col[e + 3];
        float4 a = bfu4_to_f4(h4[(size_t)j0 * 32 + lane]);
        float4 b = bfu4_to_f4(h4[(size_t)j1 * 32 + lane]);
        float4 c = bfu4_to_f4(h4[(size_t)j2 * 32 + lane]);
        float4 d = bfu4_to_f4(h4[(size_t)j3 * 32 + lane]);
        acc.x += (a.x + b.x) + (c.x + d.x);
        acc.y += (a.y + b.y) + (c.y + d.y);
        acc.z += (a.z + b.z) + (c.z + d.z);
        acc.w += (a.w + b.w) + (c.w + d.w);
    }
    for (; e < end; ++e) {
        int j = col[e];
        float4 a = bfu4_to_f4(h4[(size_t)j * 32 + lane]);
        acc.x += a.x;
        acc.y += a.y;
        acc.z += a.z;
        acc.w += a.w;
    }
    float dv = dinv[g];
    float4 bb = ((const float4*)bias)[lane];
    ushort4 o;
    o.x = f2bf(fmaxf(fmaf(acc.x, dv, bb.x), 0.f));
    o.y = f2bf(fmaxf(fmaf(acc.y, dv, bb.y), 0.f));
    o.z = f2bf(fmaxf(fmaf(acc.z, dv, bb.z), 0.f));
    o.w = f2bf(fmaxf(fmaf(acc.w, dv, bb.w), 0.f));
    ((ushort4*)out)[(size_t)g * 32 + lane] = o;
}

// pooling: each 32-lane group handles 32 consecutive nodes (bf16 in, f32 atomics out)
__global__ __launch_bounds__(256) void pool_bf16(const unsigned short* __restrict__ r2,
                                                 const int* __restrict__ batch,
                                                 float* __restrict__ ps,
                                                 int* __restrict__ pc, int N) {
    int grp = (int)((blockIdx.x * 256 + threadIdx.x) >> 5);
    int lane = threadIdx.x & 31;
    int n0 = grp * 32;
    if (n0 >= N) return;
    int n1 = min(n0 + 32, N);
    const ushort4* r4 = (const ushort4*)r2;
    float4 acc = make_float4(0.f, 0.f, 0.f, 0.f);
    int curg = batch[n0];
    int cnt = 0;
    for (int n = n0; n < n1; ++n) {
        int gph = batch[n];
        if (gph != curg) {
            atomicAdd(&ps[curg * 128 + lane * 4 + 0], acc.x);
            atomicAdd(&ps[curg * 128 + lane * 4 + 1], acc.y);
            atomicAdd(&ps[curg * 128 + lane * 4 + 2], acc.z);
            atomicAdd(&ps[curg * 128 + lane * 4 + 3], acc.w);
            if (lane == 0) atomicAdd(&pc[curg], cnt);
            acc = make_float4(0.f, 0.f, 0.f, 0.f);
            cnt = 0;
            curg = gph;
        }
        float4 v = bfu4_to_f4(r4[(size_t)n * 32 + lane]);
        acc.x += v.x;
        acc.y += v.y;
        acc.z += v.z;
        acc.w += v.w;
        cnt++;
    }
    atomicAdd(&ps[curg * 128 + lane * 4 + 0], acc.x);
    atomicAdd(&ps[curg * 128 + lane * 4 + 1], acc.y);
    atomicAdd(&ps[curg * 128 + lane * 4 + 2], acc.z);
    atomicAdd(&ps[curg * 128 + lane * 4 + 3], acc.w);
    if (lane == 0) atomicAdd(&pc[curg], cnt);
}

// out[g] = (ps[g] . Wlin) / max(pc[g],1) + blin   — one wave per graph
__global__ __launch_bounds__(256) void final_kernel(const float* __restrict__ ps,
                                                    const int* __restrict__ pc,
                                                    const float* __restrict__ Wlin,
                                                    const float* __restrict__ blin,
                                                    float* __restrict__ out, int G) {
    int g = (int)((blockIdx.x * 256 + threadIdx.x) >> 6);
    int lane = threadIdx.x & 63;
    if (g >= G) return;
    float2 s = ((const float2*)ps)[g * 64 + lane];
    float2 w = ((const float2*)Wlin)[lane];
    float v = s.x * w.x + s.y * w.y;
#pragma unroll
    for (int off = 32; off > 0; off >>= 1) v += __shfl_down(v, off);
    if (lane == 0) {
        float c = (float)max(pc[g], 1);
        out[g] = v / c + blin[0];
    }
}

extern "C" void kernel_launch(void* const* d_in, const int* in_sizes, int n_in,
                              void* d_out, int out_size, void* d_ws, size_t ws_size,
                              hipStream_t stream) {
    const float* x    = (const float*)d_in[0];
    const float* W1   = (const float*)d_in[1];
    const float* b1   = (const float*)d_in[2];
    const float* W2   = (const float*)d_in[3];
    const float* b2   = (const float*)d_in[4];
    const float* Wlin = (const float*)d_in[5];
    const float* blin = (const float*)d_in[6];
    const int*   ei   = (const int*)d_in[7];   // [2, E]
    const int*   batch= (const int*)d_in[8];   // [N]

    const int N = in_sizes[0] / 128;
    const int E = in_sizes[7] / 2;
    const int G = out_size;

    const int* srcp = ei;
    const int* dstp = ei + E;

    char* w = (char*)d_ws;
    size_t off = 0;
    auto carve = [&](size_t bytes) {
        size_t o = off;
        off = (off + bytes + 255) & ~(size_t)255;
        return (void*)(w + o);
    };
    unsigned short* bufA = (unsigned short*)carve((size_t)N * 128 * 2);  // hs (bf16)
    unsigned short* bufB = (unsigned short*)carve((size_t)N * 128 * 2);  // relu out (bf16)
    float* dinv = (float*)carve((size_t)N * 4);
    int*   cnt  = (int*)carve((size_t)N * 4);
    int*   rp   = (int*)carve((size_t)(N + 1) * 4);
    int*   bsum = (int*)carve(1024 * 4);
    int*   col  = (int*)carve((size_t)E * 4);
    float* ps   = (float*)carve((size_t)G * 128 * 4);
    int*   pc   = (int*)carve((size_t)G * 4);
    (void)ws_size;

    const int nb = (N + 1023) / 1024;

    hipMemsetAsync(cnt, 0, (size_t)N * 4, stream);
    hist_kernel<<<2048, 256, 0, stream>>>(dstp, E, cnt);
    dinv_kernel<<<(N + 255) / 256, 256, 0, stream>>>(cnt, dinv, N);
    scan1_kernel<<<nb, 1024, 0, stream>>>(cnt, rp, bsum, N);
    scan2_kernel<<<1, 1024, 0, stream>>>(bsum, nb);
    scan3_kernel<<<nb, 1024, 0, stream>>>(rp, bsum, N);
    hipMemsetAsync(cnt, 0, (size_t)N * 4, stream);
    fill_kernel<<<2048, 256, 0, stream>>>(srcp, dstp, E, rp, cnt, col);

    const int gemm_grid = (N + 63) / 64;
    const int agg_grid  = (int)(((size_t)N * 32 + 255) / 256);

    // layer 1
    gemm128_f32A<<<gemm_grid, 256, 0, stream>>>(x, W1, dinv, bufA, N);
    agg_bf16<<<agg_grid, 256, 0, stream>>>(bufA, dinv, rp, col, b1, bufB, N);
    // layer 2
    gemm128_bf16A<<<gemm_grid, 256, 0, stream>>>(bufB, W2, dinv, bufA, N);
    agg_bf16<<<agg_grid, 256, 0, stream>>>(bufA, dinv, rp, col, b2, bufB, N);

    // pooling
    hipMemsetAsync(ps, 0, (size_t)G * 128 * 4, stream);
    hipMemsetAsync(pc, 0, (size_t)G * 4, stream);
    const int ngrp = (N + 31) / 32;
    pool_bf16<<<(int)(((size_t)ngrp * 32 + 255) / 256), 256, 0, stream>>>(bufB, batch, ps, pc, N);

    final_kernel<<<(G * 64 + 255) / 256, 256, 0, stream>>>(ps, pc, Wlin, blin, (float*)d_out, G);
}

// Round 3
// 352.718 us; speedup vs baseline: 1.6378x; 1.3217x over previous
//
#include <hip/hip_runtime.h>
#include <hip/hip_bf16.h>

// ---------------------------------------------------------------------------
// GCN 2-layer + mean-pool + linear head. f32 math, bf16 intermediate storage.
// CSR built per call via LDS-binned counting sort (no scattered global atomics):
//   A. bucket histogram (dst>>9) via LDS                     -> bcnt
//   B. bucket scan (1 block)                                 -> bptr, bcur
//   C. partition edges into buckets, packed u32 (dL<<23)|src -> pairs
//   D1. per-bucket LDS node-count -> cnt, dinv (coalesced writes)
//       node scan (3 kernels) -> rp
//   D2. per-bucket scatter pairs -> col (writes stay in 33KB window per WG)
// Then: gemm (dinv fused) -> agg (pull gather) x2 -> pool -> head.
// ---------------------------------------------------------------------------

#define NBS 9            // 512 nodes per bucket
#define NPB 512
#define PART_TILE 4096   // edges per partition tile (256 thr x 16)

__device__ __forceinline__ float bf2f(unsigned short u) {
    return __uint_as_float(((unsigned int)u) << 16);
}
__device__ __forceinline__ unsigned short f2bf(float f) {
    unsigned int u = __float_as_uint(f);
    return (unsigned short)((u + 0x7FFFu + ((u >> 16) & 1u)) >> 16);
}
__device__ __forceinline__ float4 bfu4_to_f4(ushort4 v) {
    return make_float4(bf2f(v.x), bf2f(v.y), bf2f(v.z), bf2f(v.w));
}

// A: per-bucket edge counts
__global__ __launch_bounds__(256) void bucket_count(const int* __restrict__ dst, int E,
                                                    int* __restrict__ bcnt, int B) {
    __shared__ int h[1024];
    for (int i = threadIdx.x; i < B; i += 256) h[i] = 0;
    __syncthreads();
    int i = blockIdx.x * 256 + threadIdx.x;
    int stride = gridDim.x * 256;
    for (; i < E; i += stride) atomicAdd(&h[dst[i] >> NBS], 1);
    __syncthreads();
    for (int i2 = threadIdx.x; i2 < B; i2 += 256)
        if (h[i2]) atomicAdd(&bcnt[i2], h[i2]);
}

// B: exclusive scan of bucket counts (B <= 1024)
__global__ __launch_bounds__(1024) void bscan_kernel(const int* __restrict__ bcnt,
                                                     int* __restrict__ bptr,
                                                     int* __restrict__ bcur, int B) {
    __shared__ int s[1024];
    int t = threadIdx.x;
    int v = (t < B) ? bcnt[t] : 0;
    s[t] = v;
    __syncthreads();
    for (int off = 1; off < 1024; off <<= 1) {
        int x = (t >= off) ? s[t - off] : 0;
        __syncthreads();
        s[t] += x;
        __syncthreads();
    }
    if (t < B) {
        int excl = s[t] - v;
        bptr[t] = excl;
        bcur[t] = excl;
    }
    if (t == 0) bptr[B] = s[1023];
}

// C: partition edges into bucket regions as packed u32 (dstLocal<<23)|src
__global__ __launch_bounds__(256) void partition_kernel(const int* __restrict__ src,
                                                        const int* __restrict__ dst, int E,
                                                        int* __restrict__ bcur,
                                                        unsigned int* __restrict__ pairs,
                                                        int B) {
    __shared__ int h[1024];
    __shared__ int rankbase[1024];
    int t = threadIdx.x;
    int tile0 = blockIdx.x * PART_TILE;
    for (int i = t; i < B; i += 256) h[i] = 0;
    __syncthreads();

    int bk[16];
    int rk[16];
    unsigned int pk[16];
#pragma unroll
    for (int j = 0; j < 16; ++j) {
        int idx = tile0 + j * 256 + t;
        bk[j] = -1;
        if (idx < E) {
            int d = dst[idx];
            int s = src[idx];
            bk[j] = d >> NBS;
            pk[j] = ((unsigned int)(d & (NPB - 1)) << 23) | (unsigned int)s;
            rk[j] = atomicAdd(&h[bk[j]], 1);
        }
    }
    __syncthreads();
    for (int i = t; i < B; i += 256) rankbase[i] = h[i] ? atomicAdd(&bcur[i], h[i]) : 0;
    __syncthreads();
#pragma unroll
    for (int j = 0; j < 16; ++j)
        if (bk[j] >= 0) pairs[rankbase[bk[j]] + rk[j]] = pk[j];
}

// D1: per-bucket node counts + dinv (coalesced writes, no global atomics)
__global__ __launch_bounds__(256) void bucket_hist(const unsigned int* __restrict__ pairs,
                                                   const int* __restrict__ bptr,
                                                   int* __restrict__ cnt,
                                                   float* __restrict__ dinv, int N) {
    __shared__ int c[NPB];
    int b = blockIdx.x;
    for (int i = threadIdx.x; i < NPB; i += 256) c[i] = 0;
    __syncthreads();
    int s = bptr[b], e = bptr[b + 1];
    for (int i = s + threadIdx.x; i < e; i += 256) atomicAdd(&c[pairs[i] >> 23], 1);
    __syncthreads();
    int base = b << NBS;
    for (int i = threadIdx.x; i < NPB; i += 256) {
        int node = base + i;
        if (node < N) {
            cnt[node] = c[i];
            dinv[node] = rsqrtf((float)c[i] + 1.0f);
        }
    }
}

__global__ __launch_bounds__(1024) void scan1_kernel(const int* __restrict__ cnt,
                                                     int* __restrict__ rp,
                                                     int* __restrict__ bsum, int N) {
    __shared__ int s[1024];
    int t = threadIdx.x;
    int i = blockIdx.x * 1024 + t;
    int v = (i < N) ? cnt[i] : 0;
    s[t] = v;
    __syncthreads();
    for (int off = 1; off < 1024; off <<= 1) {
        int x = (t >= off) ? s[t - off] : 0;
        __syncthreads();
        s[t] += x;
        __syncthreads();
    }
    if (i < N) rp[i + 1] = s[t];
    if (t == 1023) bsum[blockIdx.x] = s[1023];
}

__global__ __launch_bounds__(1024) void scan2_kernel(int* __restrict__ bsum, int nb) {
    __shared__ int s[1024];
    int t = threadIdx.x;
    int v = (t < nb) ? bsum[t] : 0;
    s[t] = v;
    __syncthreads();
    for (int off = 1; off < 1024; off <<= 1) {
        int x = (t >= off) ? s[t - off] : 0;
        __syncthreads();
        s[t] += x;
        __syncthreads();
    }
    if (t < nb) bsum[t] = s[t] - v;
}

__global__ __launch_bounds__(1024) void scan3_kernel(int* __restrict__ rp,
                                                     const int* __restrict__ bsum, int N) {
    int i = blockIdx.x * 1024 + threadIdx.x;
    if (i < N) rp[i + 1] += bsum[blockIdx.x];
    if (i == 0) rp[0] = 0;
}

// D2: per-bucket scatter into col (writes confined to this bucket's col window)
__global__ __launch_bounds__(256) void bucket_scatter(const unsigned int* __restrict__ pairs,
                                                      const int* __restrict__ bptr,
                                                      const int* __restrict__ rp,
                                                      int* __restrict__ col, int N) {
    __shared__ int cur[NPB];
    __shared__ int rpl[NPB];
    int b = blockIdx.x;
    int base = b << NBS;
    for (int i = threadIdx.x; i < NPB; i += 256) {
        cur[i] = 0;
        int node = base + i;
        rpl[i] = (node < N) ? rp[node] : 0;
    }
    __syncthreads();
    int s = bptr[b], e = bptr[b + 1];
    for (int i = s + threadIdx.x; i < e; i += 256) {
        unsigned int p = pairs[i];
        int dL = (int)(p >> 23);
        int sn = (int)(p & 0x7FFFFFu);
        int r = atomicAdd(&cur[dL], 1);
        col[rpl[dL] + r] = sn;
    }
}

// hs[row][c] = bf16((sum_k A[row][k]*W[k][c]) * dinv[row])  — A f32
__global__ __launch_bounds__(256) void gemm128_f32A(const float* __restrict__ A,
                                                    const float* __restrict__ W,
                                                    const float* __restrict__ dinv,
                                                    unsigned short* __restrict__ C, int M) {
    __shared__ float Xt[64][68];
    __shared__ float Wt[64][128];
    int t = threadIdx.x;
    int r0 = blockIdx.x * 64;
    int cg = t & 31;
    int rg = t >> 5;
    float acc[8][4];
#pragma unroll
    for (int i = 0; i < 8; ++i)
#pragma unroll
        for (int j = 0; j < 4; ++j) acc[i][j] = 0.f;

    for (int kt = 0; kt < 128; kt += 64) {
#pragma unroll
        for (int i = 0; i < 4; ++i) {
            int lin = (t + i * 256) * 4;
            int r = lin >> 6;
            int kk = lin & 63;
            float4 v = make_float4(0.f, 0.f, 0.f, 0.f);
            int row = r0 + r;
            if (row < M) v = *(const float4*)&A[(size_t)row * 128 + kt + kk];
            *(float4*)&Xt[r][kk] = v;
        }
#pragma unroll
        for (int i = 0; i < 8; ++i) {
            int lin = (t + i * 256) * 4;
            int r = lin >> 7;
            int c = lin & 127;
            *(float4*)&Wt[r][c] = *(const float4*)&W[(kt + r) * 128 + c];
        }
        __syncthreads();
#pragma unroll 8
        for (int k = 0; k < 64; ++k) {
            float4 w = *(const float4*)&Wt[k][cg * 4];
#pragma unroll
            for (int i = 0; i < 8; ++i) {
                float xs = Xt[rg * 8 + i][k];
                acc[i][0] = fmaf(xs, w.x, acc[i][0]);
                acc[i][1] = fmaf(xs, w.y, acc[i][1]);
                acc[i][2] = fmaf(xs, w.z, acc[i][2]);
                acc[i][3] = fmaf(xs, w.w, acc[i][3]);
            }
        }
        __syncthreads();
    }
#pragma unroll
    for (int i = 0; i < 8; ++i) {
        int row = r0 + rg * 8 + i;
        if (row < M) {
            float d = dinv[row];
            ushort4 o;
            o.x = f2bf(acc[i][0] * d);
            o.y = f2bf(acc[i][1] * d);
            o.z = f2bf(acc[i][2] * d);
            o.w = f2bf(acc[i][3] * d);
            *(ushort4*)&C[(size_t)row * 128 + cg * 4] = o;
        }
    }
}

// same, A bf16
__global__ __launch_bounds__(256) void gemm128_bf16A(const unsigned short* __restrict__ A,
                                                     const float* __restrict__ W,
                                                     const float* __restrict__ dinv,
                                                     unsigned short* __restrict__ C, int M) {
    __shared__ float Xt[64][68];
    __shared__ float Wt[64][128];
    int t = threadIdx.x;
    int r0 = blockIdx.x * 64;
    int cg = t & 31;
    int rg = t >> 5;
    float acc[8][4];
#pragma unroll
    for (int i = 0; i < 8; ++i)
#pragma unroll
        for (int j = 0; j < 4; ++j) acc[i][j] = 0.f;

    for (int kt = 0; kt < 128; kt += 64) {
#pragma unroll
        for (int i = 0; i < 4; ++i) {
            int lin = (t + i * 256) * 4;
            int r = lin >> 6;
            int kk = lin & 63;
            float4 v = make_float4(0.f, 0.f, 0.f, 0.f);
            int row = r0 + r;
            if (row < M) {
                ushort4 u = *(const ushort4*)&A[(size_t)row * 128 + kt + kk];
                v = bfu4_to_f4(u);
            }
            *(float4*)&Xt[r][kk] = v;
        }
#pragma unroll
        for (int i = 0; i < 8; ++i) {
            int lin = (t + i * 256) * 4;
            int r = lin >> 7;
            int c = lin & 127;
            *(float4*)&Wt[r][c] = *(const float4*)&W[(kt + r) * 128 + c];
        }
        __syncthreads();
#pragma unroll 8
        for (int k = 0; k < 64; ++k) {
            float4 w = *(const float4*)&Wt[k][cg * 4];
#pragma unroll
            for (int i = 0; i < 8; ++i) {
                float xs = Xt[rg * 8 + i][k];
                acc[i][0] = fmaf(xs, w.x, acc[i][0]);
                acc[i][1] = fmaf(xs, w.y, acc[i][1]);
                acc[i][2] = fmaf(xs, w.z, acc[i][2]);
                acc[i][3] = fmaf(xs, w.w, acc[i][3]);
            }
        }
        __syncthreads();
    }
#pragma unroll
    for (int i = 0; i < 8; ++i) {
        int row = r0 + rg * 8 + i;
        if (row < M) {
            float d = dinv[row];
            ushort4 o;
            o.x = f2bf(acc[i][0] * d);
            o.y = f2bf(acc[i][1] * d);
            o.z = f2bf(acc[i][2] * d);
            o.w = f2bf(acc[i][3] * d);
            *(ushort4*)&C[(size_t)row * 128 + cg * 4] = o;
        }
    }
}

// pull aggregation, bf16 in/out: one 32-lane group per node
__global__ __launch_bounds__(256) void agg_bf16(const unsigned short* __restrict__ hs,
                                                const float* __restrict__ dinv,
                                                const int* __restrict__ rp,
                                                const int* __restrict__ col,
                                                const float* __restrict__ bias,
                                                unsigned short* __restrict__ out, int N) {
    int g = (int)((blockIdx.x * 256 + threadIdx.x) >> 5);
    int lane = threadIdx.x & 31;
    if (g >= N) return;
    const ushort4* h4 = (const ushort4*)hs;
    float4 acc = bfu4_to_f4(h4[(size_t)g * 32 + lane]);  // self (hs_i)
    int e = rp[g], end = rp[g + 1];
    for (; e + 3 < end; e += 4) {
        int j0 = col[e], j1 = col[e + 1], j2 = col[e + 2], j3 = col[e + 3];
        float4 a = bfu4_to_f4(h4[(size_t)j0 * 32 + lane]);
        float4 b = bfu4_to_f4(h4[(size_t)j1 * 32 + lane]);
        float4 c = bfu4_to_f4(h4[(size_t)j2 * 32 + lane]);
        float4 d = bfu4_to_f4(h4[(size_t)j3 * 32 + lane]);
        acc.x += (a.x + b.x) + (c.x + d.x);
        acc.y += (a.y + b.y) + (c.y + d.y);
        acc.z += (a.z + b.z) + (c.z + d.z);
        acc.w += (a.w + b.w) + (c.w + d.w);
    }
    for (; e < end; ++e) {
        int j = col[e];
        float4 a = bfu4_to_f4(h4[(size_t)j * 32 + lane]);
        acc.x += a.x;
        acc.y += a.y;
        acc.z += a.z;
        acc.w += a.w;
    }
    float dv = dinv[g];
    float4 bb = ((const float4*)bias)[lane];
    ushort4 o;
    o.x = f2bf(fmaxf(fmaf(acc.x, dv, bb.x), 0.f));
    o.y = f2bf(fmaxf(fmaf(acc.y, dv, bb.y), 0.f));
    o.z = f2bf(fmaxf(fmaf(acc.z, dv, bb.z), 0.f));
    o.w = f2bf(fmaxf(fmaf(acc.w, dv, bb.w), 0.f));
    ((ushort4*)out)[(size_t)g * 32 + lane] = o;
}

// pooling: each 32-lane group handles 32 consecutive nodes
__global__ __launch_bounds__(256) void pool_bf16(const unsigned short* __restrict__ r2,
                                                 const int* __restrict__ batch,
                                                 float* __restrict__ ps,
                                                 int* __restrict__ pc, int N) {
    int grp = (int)((blockIdx.x * 256 + threadIdx.x) >> 5);
    int lane = threadIdx.x & 31;
    int n0 = grp * 32;
    if (n0 >= N) return;
    int n1 = min(n0 + 32, N);
    const ushort4* r4 = (const ushort4*)r2;
    float4 acc = make_float4(0.f, 0.f, 0.f, 0.f);
    int curg = batch[n0];
    int cnt = 0;
    for (int n = n0; n < n1; ++n) {
        int gph = batch[n];
        if (gph != curg) {
            atomicAdd(&ps[curg * 128 + lane * 4 + 0], acc.x);
            atomicAdd(&ps[curg * 128 + lane * 4 + 1], acc.y);
            atomicAdd(&ps[curg * 128 + lane * 4 + 2], acc.z);
            atomicAdd(&ps[curg * 128 + lane * 4 + 3], acc.w);
            if (lane == 0) atomicAdd(&pc[curg], cnt);
            acc = make_float4(0.f, 0.f, 0.f, 0.f);
            cnt = 0;
            curg = gph;
        }
        float4 v = bfu4_to_f4(r4[(size_t)n * 32 + lane]);
        acc.x += v.x;
        acc.y += v.y;
        acc.z += v.z;
        acc.w += v.w;
        cnt++;
    }
    atomicAdd(&ps[curg * 128 + lane * 4 + 0], acc.x);
    atomicAdd(&ps[curg * 128 + lane * 4 + 1], acc.y);
    atomicAdd(&ps[curg * 128 + lane * 4 + 2], acc.z);
    atomicAdd(&ps[curg * 128 + lane * 4 + 3], acc.w);
    if (lane == 0) atomicAdd(&pc[curg], cnt);
}

__global__ __launch_bounds__(256) void final_kernel(const float* __restrict__ ps,
                                                    const int* __restrict__ pc,
                                                    const float* __restrict__ Wlin,
                                                    const float* __restrict__ blin,
                                                    float* __restrict__ out, int G) {
    int g = (int)((blockIdx.x * 256 + threadIdx.x) >> 6);
    int lane = threadIdx.x & 63;
    if (g >= G) return;
    float2 s = ((const float2*)ps)[g * 64 + lane];
    float2 w = ((const float2*)Wlin)[lane];
    float v = s.x * w.x + s.y * w.y;
#pragma unroll
    for (int off = 32; off > 0; off >>= 1) v += __shfl_down(v, off);
    if (lane == 0) {
        float c = (float)max(pc[g], 1);
        out[g] = v / c + blin[0];
    }
}

extern "C" void kernel_launch(void* const* d_in, const int* in_sizes, int n_in,
                              void* d_out, int out_size, void* d_ws, size_t ws_size,
                              hipStream_t stream) {
    const float* x    = (const float*)d_in[0];
    const float* W1   = (const float*)d_in[1];
    const float* b1   = (const float*)d_in[2];
    const float* W2   = (const float*)d_in[3];
    const float* b2   = (const float*)d_in[4];
    const float* Wlin = (const float*)d_in[5];
    const float* blin = (const float*)d_in[6];
    const int*   ei   = (const int*)d_in[7];   // [2, E]
    const int*   batch= (const int*)d_in[8];   // [N]

    const int N = in_sizes[0] / 128;
    const int E = in_sizes[7] / 2;
    const int G = out_size;
    const int B = (N + NPB - 1) >> NBS;        // buckets (196 for N=100k)

    const int* srcp = ei;
    const int* dstp = ei + E;

    char* w = (char*)d_ws;
    size_t off = 0;
    auto carve = [&](size_t bytes) {
        size_t o = off;
        off = (off + bytes + 255) & ~(size_t)255;
        return (void*)(w + o);
    };
    unsigned short* bufA = (unsigned short*)carve((size_t)N * 128 * 2);
    unsigned short* bufB = (unsigned short*)carve((size_t)N * 128 * 2);
    float* dinv = (float*)carve((size_t)N * 4);
    int*   cnt  = (int*)carve((size_t)N * 4);
    int*   rp   = (int*)carve((size_t)(N + 1) * 4);
    int*   bsum = (int*)carve(1024 * 4);
    int*   col  = (int*)carve((size_t)E * 4);
    unsigned int* pairs = (unsigned int*)carve((size_t)E * 4);
    int*   bcnt = (int*)carve((size_t)(B + 1) * 4);
    int*   bptr = (int*)carve((size_t)(B + 1) * 4);
    int*   bcur = (int*)carve((size_t)(B + 1) * 4);
    float* ps   = (float*)carve((size_t)G * 128 * 4);
    int*   pc   = (int*)carve((size_t)G * 4);
    (void)ws_size;

    const int nb = (N + 1023) / 1024;
    const int ntiles = (E + PART_TILE - 1) / PART_TILE;

    // CSR build (binned)
    hipMemsetAsync(bcnt, 0, (size_t)(B + 1) * 4, stream);
    bucket_count<<<1024, 256, 0, stream>>>(dstp, E, bcnt, B);
    bscan_kernel<<<1, 1024, 0, stream>>>(bcnt, bptr, bcur, B);
    partition_kernel<<<ntiles, 256, 0, stream>>>(srcp, dstp, E, bcur, pairs, B);
    bucket_hist<<<B, 256, 0, stream>>>(pairs, bptr, cnt, dinv, N);
    scan1_kernel<<<nb, 1024, 0, stream>>>(cnt, rp, bsum, N);
    scan2_kernel<<<1, 1024, 0, stream>>>(bsum, nb);
    scan3_kernel<<<nb, 1024, 0, stream>>>(rp, bsum, N);
    bucket_scatter<<<B, 256, 0, stream>>>(pairs, bptr, rp, col, N);

    const int gemm_grid = (N + 63) / 64;
    const int agg_grid  = (int)(((size_t)N * 32 + 255) / 256);

    // layer 1
    gemm128_f32A<<<gemm_grid, 256, 0, stream>>>(x, W1, dinv, bufA, N);
    agg_bf16<<<agg_grid, 256, 0, stream>>>(bufA, dinv, rp, col, b1, bufB, N);
    // layer 2
    gemm128_bf16A<<<gemm_grid, 256, 0, stream>>>(bufB, W2, dinv, bufA, N);
    agg_bf16<<<agg_grid, 256, 0, stream>>>(bufA, dinv, rp, col, b2, bufB, N);

    // pooling
    hipMemsetAsync(ps, 0, (size_t)G * 128 * 4, stream);
    hipMemsetAsync(pc, 0, (size_t)G * 4, stream);
    const int ngrp = (N + 31) / 32;
    pool_bf16<<<(int)(((size_t)ngrp * 32 + 255) / 256), 256, 0, stream>>>(bufB, batch, ps, pc, N);

    final_kernel<<<(G * 64 + 255) / 256, 256, 0, stream>>>(ps, pc, Wlin, blin, (float*)d_out, G);
}

// Round 4
// 279.432 us; speedup vs baseline: 2.0673x; 1.2623x over previous
//
#include <hip/hip_runtime.h>
#include <hip/hip_bf16.h>

// ---------------------------------------------------------------------------
// GCN 2-layer + mean-pool + linear head. bf16 MFMA GEMMs (f32 accumulate),
// bf16 intermediate storage, binned CSR build, pull-gather aggregation.
//   CSR: bucket_count -> bscan -> partition -> bucket_hist(+dinv) -> node scan
//        -> bucket_scatter
//   wconv: W[k][n] f32 -> Wt[n][k] bf16  (per layer)
//   gemm_mfma: hs = bf16((A @ W) * dinv[row]);  A f32 (layer1) or bf16 (layer2)
//   agg_bf16: r = bf16(relu(dinv*(sum_nbr hs + hs_self) + b))
//   pool -> final head
// ---------------------------------------------------------------------------

#define NBS 9            // 512 nodes per bucket
#define NPB 512
#define PART_TILE 4096   // edges per partition tile (256 thr x 16)

typedef __attribute__((ext_vector_type(8))) short short8;
typedef __attribute__((ext_vector_type(4))) float f32x4;

__device__ __forceinline__ float bf2f(unsigned short u) {
    return __uint_as_float(((unsigned int)u) << 16);
}
__device__ __forceinline__ unsigned short f2bf(float f) {
    unsigned int u = __float_as_uint(f);
    return (unsigned short)((u + 0x7FFFu + ((u >> 16) & 1u)) >> 16);
}
__device__ __forceinline__ float4 bfu4_to_f4(ushort4 v) {
    return make_float4(bf2f(v.x), bf2f(v.y), bf2f(v.z), bf2f(v.w));
}
__device__ __forceinline__ short8 pack_bf8(float4 a, float4 b) {
    short8 s;
    s[0] = (short)f2bf(a.x); s[1] = (short)f2bf(a.y);
    s[2] = (short)f2bf(a.z); s[3] = (short)f2bf(a.w);
    s[4] = (short)f2bf(b.x); s[5] = (short)f2bf(b.y);
    s[6] = (short)f2bf(b.z); s[7] = (short)f2bf(b.w);
    return s;
}

// ---------------- CSR build ----------------

__global__ __launch_bounds__(256) void bucket_count(const int* __restrict__ dst, int E,
                                                    int* __restrict__ bcnt, int B) {
    __shared__ int h[1024];
    for (int i = threadIdx.x; i < B; i += 256) h[i] = 0;
    __syncthreads();
    int i = blockIdx.x * 256 + threadIdx.x;
    int stride = gridDim.x * 256;
    for (; i < E; i += stride) atomicAdd(&h[dst[i] >> NBS], 1);
    __syncthreads();
    for (int i2 = threadIdx.x; i2 < B; i2 += 256)
        if (h[i2]) atomicAdd(&bcnt[i2], h[i2]);
}

__global__ __launch_bounds__(1024) void bscan_kernel(const int* __restrict__ bcnt,
                                                     int* __restrict__ bptr,
                                                     int* __restrict__ bcur, int B) {
    __shared__ int s[1024];
    int t = threadIdx.x;
    int v = (t < B) ? bcnt[t] : 0;
    s[t] = v;
    __syncthreads();
    for (int off = 1; off < 1024; off <<= 1) {
        int x = (t >= off) ? s[t - off] : 0;
        __syncthreads();
        s[t] += x;
        __syncthreads();
    }
    if (t < B) {
        int excl = s[t] - v;
        bptr[t] = excl;
        bcur[t] = excl;
    }
    if (t == 0) bptr[B] = s[1023];
}

__global__ __launch_bounds__(256) void partition_kernel(const int* __restrict__ src,
                                                        const int* __restrict__ dst, int E,
                                                        int* __restrict__ bcur,
                                                        unsigned int* __restrict__ pairs,
                                                        int B) {
    __shared__ int h[1024];
    __shared__ int rankbase[1024];
    int t = threadIdx.x;
    int tile0 = blockIdx.x * PART_TILE;
    for (int i = t; i < B; i += 256) h[i] = 0;
    __syncthreads();

    int bk[16];
    int rk[16];
    unsigned int pk[16];
#pragma unroll
    for (int j = 0; j < 16; ++j) {
        int idx = tile0 + j * 256 + t;
        bk[j] = -1;
        if (idx < E) {
            int d = dst[idx];
            int s = src[idx];
            bk[j] = d >> NBS;
            pk[j] = ((unsigned int)(d & (NPB - 1)) << 23) | (unsigned int)s;
            rk[j] = atomicAdd(&h[bk[j]], 1);
        }
    }
    __syncthreads();
    for (int i = t; i < B; i += 256) rankbase[i] = h[i] ? atomicAdd(&bcur[i], h[i]) : 0;
    __syncthreads();
#pragma unroll
    for (int j = 0; j < 16; ++j)
        if (bk[j] >= 0) pairs[rankbase[bk[j]] + rk[j]] = pk[j];
}

__global__ __launch_bounds__(256) void bucket_hist(const unsigned int* __restrict__ pairs,
                                                   const int* __restrict__ bptr,
                                                   int* __restrict__ cnt,
                                                   float* __restrict__ dinv, int N) {
    __shared__ int c[NPB];
    int b = blockIdx.x;
    for (int i = threadIdx.x; i < NPB; i += 256) c[i] = 0;
    __syncthreads();
    int s = bptr[b], e = bptr[b + 1];
    for (int i = s + threadIdx.x; i < e; i += 256) atomicAdd(&c[pairs[i] >> 23], 1);
    __syncthreads();
    int base = b << NBS;
    for (int i = threadIdx.x; i < NPB; i += 256) {
        int node = base + i;
        if (node < N) {
            cnt[node] = c[i];
            dinv[node] = rsqrtf((float)c[i] + 1.0f);
        }
    }
}

__global__ __launch_bounds__(1024) void scan1_kernel(const int* __restrict__ cnt,
                                                     int* __restrict__ rp,
                                                     int* __restrict__ bsum, int N) {
    __shared__ int s[1024];
    int t = threadIdx.x;
    int i = blockIdx.x * 1024 + t;
    int v = (i < N) ? cnt[i] : 0;
    s[t] = v;
    __syncthreads();
    for (int off = 1; off < 1024; off <<= 1) {
        int x = (t >= off) ? s[t - off] : 0;
        __syncthreads();
        s[t] += x;
        __syncthreads();
    }
    if (i < N) rp[i + 1] = s[t];
    if (t == 1023) bsum[blockIdx.x] = s[1023];
}

__global__ __launch_bounds__(1024) void scan2_kernel(int* __restrict__ bsum, int nb) {
    __shared__ int s[1024];
    int t = threadIdx.x;
    int v = (t < nb) ? bsum[t] : 0;
    s[t] = v;
    __syncthreads();
    for (int off = 1; off < 1024; off <<= 1) {
        int x = (t >= off) ? s[t - off] : 0;
        __syncthreads();
        s[t] += x;
        __syncthreads();
    }
    if (t < nb) bsum[t] = s[t] - v;
}

__global__ __launch_bounds__(1024) void scan3_kernel(int* __restrict__ rp,
                                                     const int* __restrict__ bsum, int N) {
    int i = blockIdx.x * 1024 + threadIdx.x;
    if (i < N) rp[i + 1] += bsum[blockIdx.x];
    if (i == 0) rp[0] = 0;
}

__global__ __launch_bounds__(256) void bucket_scatter(const unsigned int* __restrict__ pairs,
                                                      const int* __restrict__ bptr,
                                                      const int* __restrict__ rp,
                                                      int* __restrict__ col, int N) {
    __shared__ int cur[NPB];
    __shared__ int rpl[NPB];
    int b = blockIdx.x;
    int base = b << NBS;
    for (int i = threadIdx.x; i < NPB; i += 256) {
        cur[i] = 0;
        int node = base + i;
        rpl[i] = (node < N) ? rp[node] : 0;
    }
    __syncthreads();
    int s = bptr[b], e = bptr[b + 1];
    for (int i = s + threadIdx.x; i < e; i += 256) {
        unsigned int p = pairs[i];
        int dL = (int)(p >> 23);
        int sn = (int)(p & 0x7FFFFFu);
        int r = atomicAdd(&cur[dL], 1);
        col[rpl[dL] + r] = sn;
    }
}

// ---------------- GEMM (MFMA) ----------------

// Wt[n][k] = bf16(W[k][n])
__global__ void wconv_kernel(const float* __restrict__ W, unsigned short* __restrict__ Wt) {
    int n = blockIdx.x;
    int k = threadIdx.x;
    Wt[n * 128 + k] = f2bf(W[k * 128 + n]);
}

// C[row][c] = bf16((sum_k A[row][k]*W[k][c]) * dinv[row])
// Wt: global bf16 [128 cols][128 k]. A: f32 or bf16 [M][128].
// LDS: Wt swizzled (byte ^= (row&7)<<4 within 256B rows) -> conflict-free
// ds_read_b128 B-fragments. A fragments loaded straight from global.
template <bool A_F32>
__global__ __launch_bounds__(256) void gemm_mfma(const void* __restrict__ Ap,
                                                 const unsigned short* __restrict__ Wt,
                                                 const float* __restrict__ dinv,
                                                 unsigned short* __restrict__ C, int M) {
    __shared__ unsigned char lds[32768];
    int t = threadIdx.x;
    // stage Wt with swizzle: 2048 16B chunks
#pragma unroll
    for (int i = 0; i < 8; ++i) {
        int c = t + i * 256;
        int row = c >> 4;             // 16 chunks per 256B row
        int b = (c & 15) << 4;
        int4 v = ((const int4*)Wt)[c];
        *(int4*)&lds[row * 256 + (b ^ ((row & 7) << 4))] = v;
    }

    int lane = t & 63;
    int wv = t >> 6;
    int r0 = blockIdx.x * 128 + wv * 32;
    int l15 = lane & 15;
    int kg = lane >> 4;  // 0..3

    // A fragments: lane holds A[row = r0+rf*16+l15][k = kk*32 + kg*8 + e]
    short8 af[2][4];
#pragma unroll
    for (int rf = 0; rf < 2; ++rf) {
        int row = r0 + rf * 16 + l15;
        row = row < M ? row : M - 1;
#pragma unroll
        for (int kk = 0; kk < 4; ++kk) {
            size_t eoff = (size_t)row * 128 + kk * 32 + kg * 8;
            if constexpr (A_F32) {
                const float* A = (const float*)Ap;
                float4 v0 = *(const float4*)(A + eoff);
                float4 v1 = *(const float4*)(A + eoff + 4);
                af[rf][kk] = pack_bf8(v0, v1);
            } else {
                af[rf][kk] = *(const short8*)((const unsigned short*)Ap + eoff);
            }
        }
    }
    __syncthreads();

    f32x4 acc[2][8];
#pragma unroll
    for (int rf = 0; rf < 2; ++rf)
#pragma unroll
        for (int cf = 0; cf < 8; ++cf) acc[rf][cf] = (f32x4)(0.f);

#pragma unroll
    for (int cf = 0; cf < 8; ++cf) {
        short8 bfr[4];
#pragma unroll
        for (int kk = 0; kk < 4; ++kk) {
            int brow = cf * 16 + l15;
            int bb = kk * 64 + kg * 16;
            bfr[kk] = *(const short8*)&lds[brow * 256 + (bb ^ ((brow & 7) << 4))];
        }
#pragma unroll
        for (int kk = 0; kk < 4; ++kk) {
#pragma unroll
            for (int rf = 0; rf < 2; ++rf)
                acc[rf][cf] = __builtin_amdgcn_mfma_f32_16x16x32_bf16(af[rf][kk], bfr[kk],
                                                                      acc[rf][cf], 0, 0, 0);
        }
    }

    // epilogue: D[row=(kg*4+r)][col=l15] per 16x16 frag
#pragma unroll
    for (int rf = 0; rf < 2; ++rf) {
#pragma unroll
        for (int r = 0; r < 4; ++r) {
            int row = r0 + rf * 16 + kg * 4 + r;
            if (row < M) {
                float dv = dinv[row];
#pragma unroll
                for (int cf = 0; cf < 8; ++cf)
                    C[(size_t)row * 128 + cf * 16 + l15] = f2bf(acc[rf][cf][r] * dv);
            }
        }
    }
}

// ---------------- aggregation / pool / head ----------------

__global__ __launch_bounds__(256) void agg_bf16(const unsigned short* __restrict__ hs,
                                                const float* __restrict__ dinv,
                                                const int* __restrict__ rp,
                                                const int* __restrict__ col,
                                                const float* __restrict__ bias,
                                                unsigned short* __restrict__ out, int N) {
    int g = (int)((blockIdx.x * 256 + threadIdx.x) >> 5);
    int lane = threadIdx.x & 31;
    if (g >= N) return;
    const ushort4* h4 = (const ushort4*)hs;
    float4 acc = bfu4_to_f4(h4[(size_t)g * 32 + lane]);  // self (hs_i)
    int e = rp[g], end = rp[g + 1];
    for (; e + 3 < end; e += 4) {
        int j0 = col[e], j1 = col[e + 1], j2 = col[e + 2], j3 = col[e + 3];
        float4 a = bfu4_to_f4(h4[(size_t)j0 * 32 + lane]);
        float4 b = bfu4_to_f4(h4[(size_t)j1 * 32 + lane]);
        float4 c = bfu4_to_f4(h4[(size_t)j2 * 32 + lane]);
        float4 d = bfu4_to_f4(h4[(size_t)j3 * 32 + lane]);
        acc.x += (a.x + b.x) + (c.x + d.x);
        acc.y += (a.y + b.y) + (c.y + d.y);
        acc.z += (a.z + b.z) + (c.z + d.z);
        acc.w += (a.w + b.w) + (c.w + d.w);
    }
    for (; e < end; ++e) {
        int j = col[e];
        float4 a = bfu4_to_f4(h4[(size_t)j * 32 + lane]);
        acc.x += a.x;
        acc.y += a.y;
        acc.z += a.z;
        acc.w += a.w;
    }
    float dv = dinv[g];
    float4 bb = ((const float4*)bias)[lane];
    ushort4 o;
    o.x = f2bf(fmaxf(fmaf(acc.x, dv, bb.x), 0.f));
    o.y = f2bf(fmaxf(fmaf(acc.y, dv, bb.y), 0.f));
    o.z = f2bf(fmaxf(fmaf(acc.z, dv, bb.z), 0.f));
    o.w = f2bf(fmaxf(fmaf(acc.w, dv, bb.w), 0.f));
    ((ushort4*)out)[(size_t)g * 32 + lane] = o;
}

__global__ __launch_bounds__(256) void pool_bf16(const unsigned short* __restrict__ r2,
                                                 const int* __restrict__ batch,
                                                 float* __restrict__ ps,
                                                 int* __restrict__ pc, int N) {
    int grp = (int)((blockIdx.x * 256 + threadIdx.x) >> 5);
    int lane = threadIdx.x & 31;
    int n0 = grp * 32;
    if (n0 >= N) return;
    int n1 = min(n0 + 32, N);
    const ushort4* r4 = (const ushort4*)r2;
    float4 acc = make_float4(0.f, 0.f, 0.f, 0.f);
    int curg = batch[n0];
    int cnt = 0;
    for (int n = n0; n < n1; ++n) {
        int gph = batch[n];
        if (gph != curg) {
            atomicAdd(&ps[curg * 128 + lane * 4 + 0], acc.x);
            atomicAdd(&ps[curg * 128 + lane * 4 + 1], acc.y);
            atomicAdd(&ps[curg * 128 + lane * 4 + 2], acc.z);
            atomicAdd(&ps[curg * 128 + lane * 4 + 3], acc.w);
            if (lane == 0) atomicAdd(&pc[curg], cnt);
            acc = make_float4(0.f, 0.f, 0.f, 0.f);
            cnt = 0;
            curg = gph;
        }
        float4 v = bfu4_to_f4(r4[(size_t)n * 32 + lane]);
        acc.x += v.x;
        acc.y += v.y;
        acc.z += v.z;
        acc.w += v.w;
        cnt++;
    }
    atomicAdd(&ps[curg * 128 + lane * 4 + 0], acc.x);
    atomicAdd(&ps[curg * 128 + lane * 4 + 1], acc.y);
    atomicAdd(&ps[curg * 128 + lane * 4 + 2], acc.z);
    atomicAdd(&ps[curg * 128 + lane * 4 + 3], acc.w);
    if (lane == 0) atomicAdd(&pc[curg], cnt);
}

__global__ __launch_bounds__(256) void final_kernel(const float* __restrict__ ps,
                                                    const int* __restrict__ pc,
                                                    const float* __restrict__ Wlin,
                                                    const float* __restrict__ blin,
                                                    float* __restrict__ out, int G) {
    int g = (int)((blockIdx.x * 256 + threadIdx.x) >> 6);
    int lane = threadIdx.x & 63;
    if (g >= G) return;
    float2 s = ((const float2*)ps)[g * 64 + lane];
    float2 w = ((const float2*)Wlin)[lane];
    float v = s.x * w.x + s.y * w.y;
#pragma unroll
    for (int off = 32; off > 0; off >>= 1) v += __shfl_down(v, off);
    if (lane == 0) {
        float c = (float)max(pc[g], 1);
        out[g] = v / c + blin[0];
    }
}

extern "C" void kernel_launch(void* const* d_in, const int* in_sizes, int n_in,
                              void* d_out, int out_size, void* d_ws, size_t ws_size,
                              hipStream_t stream) {
    const float* x    = (const float*)d_in[0];
    const float* W1   = (const float*)d_in[1];
    const float* b1   = (const float*)d_in[2];
    const float* W2   = (const float*)d_in[3];
    const float* b2   = (const float*)d_in[4];
    const float* Wlin = (const float*)d_in[5];
    const float* blin = (const float*)d_in[6];
    const int*   ei   = (const int*)d_in[7];   // [2, E]
    const int*   batch= (const int*)d_in[8];   // [N]

    const int N = in_sizes[0] / 128;
    const int E = in_sizes[7] / 2;
    const int G = out_size;
    const int B = (N + NPB - 1) >> NBS;

    const int* srcp = ei;
    const int* dstp = ei + E;

    char* w = (char*)d_ws;
    size_t off = 0;
    auto carve = [&](size_t bytes) {
        size_t o = off;
        off = (off + bytes + 255) & ~(size_t)255;
        return (void*)(w + o);
    };
    unsigned short* bufA = (unsigned short*)carve((size_t)N * 128 * 2);
    unsigned short* bufB = (unsigned short*)carve((size_t)N * 128 * 2);
    float* dinv = (float*)carve((size_t)N * 4);
    int*   cnt  = (int*)carve((size_t)N * 4);
    int*   rp   = (int*)carve((size_t)(N + 1) * 4);
    int*   bsum = (int*)carve(1024 * 4);
    int*   col  = (int*)carve((size_t)E * 4);
    unsigned int* pairs = (unsigned int*)carve((size_t)E * 4);
    int*   bcnt = (int*)carve((size_t)(B + 1) * 4);
    int*   bptr = (int*)carve((size_t)(B + 1) * 4);
    int*   bcur = (int*)carve((size_t)(B + 1) * 4);
    unsigned short* Wt1 = (unsigned short*)carve(128 * 128 * 2);
    unsigned short* Wt2 = (unsigned short*)carve(128 * 128 * 2);
    float* ps   = (float*)carve((size_t)G * 128 * 4);
    int*   pc   = (int*)carve((size_t)G * 4);
    (void)ws_size;

    const int nb = (N + 1023) / 1024;
    const int ntiles = (E + PART_TILE - 1) / PART_TILE;

    // CSR build (binned)
    hipMemsetAsync(bcnt, 0, (size_t)(B + 1) * 4, stream);
    bucket_count<<<1024, 256, 0, stream>>>(dstp, E, bcnt, B);
    bscan_kernel<<<1, 1024, 0, stream>>>(bcnt, bptr, bcur, B);
    partition_kernel<<<ntiles, 256, 0, stream>>>(srcp, dstp, E, bcur, pairs, B);
    bucket_hist<<<B, 256, 0, stream>>>(pairs, bptr, cnt, dinv, N);
    scan1_kernel<<<nb, 1024, 0, stream>>>(cnt, rp, bsum, N);
    scan2_kernel<<<1, 1024, 0, stream>>>(bsum, nb);
    scan3_kernel<<<nb, 1024, 0, stream>>>(rp, bsum, N);
    bucket_scatter<<<B, 256, 0, stream>>>(pairs, bptr, rp, col, N);

    // weight transpose+convert
    wconv_kernel<<<128, 128, 0, stream>>>(W1, Wt1);
    wconv_kernel<<<128, 128, 0, stream>>>(W2, Wt2);

    const int gemm_grid = (N + 127) / 128;
    const int agg_grid  = (int)(((size_t)N * 32 + 255) / 256);

    // layer 1
    gemm_mfma<true><<<gemm_grid, 256, 0, stream>>>(x, Wt1, dinv, bufA, N);
    agg_bf16<<<agg_grid, 256, 0, stream>>>(bufA, dinv, rp, col, b1, bufB, N);
    // layer 2
    gemm_mfma<false><<<gemm_grid, 256, 0, stream>>>(bufB, Wt2, dinv, bufA, N);
    agg_bf16<<<agg_grid, 256, 0, stream>>>(bufA, dinv, rp, col, b2, bufB, N);

    // pooling
    hipMemsetAsync(ps, 0, (size_t)G * 128 * 4, stream);
    hipMemsetAsync(pc, 0, (size_t)G * 4, stream);
    const int ngrp = (N + 31) / 32;
    pool_bf16<<<(int)(((size_t)ngrp * 32 + 255) / 256), 256, 0, stream>>>(bufB, batch, ps, pc, N);

    final_kernel<<<(G * 64 + 255) / 256, 256, 0, stream>>>(ps, pc, Wlin, blin, (float*)d_out, G);
}